// Round 1
// baseline (980.610 us; speedup 1.0000x reference)
//
#include <hip/hip_runtime.h>

#define NN 100000
#define NE 1600000
#define F 128
#define SCAN_CHUNK 2048
#define NB_SCAN ((NN + SCAN_CHUNK - 1) / SCAN_CHUNK)   // 49

// ---------------- CSR build ----------------
__global__ void k_hist(const int* __restrict__ dst, int* __restrict__ deg) {
    int stride = gridDim.x * blockDim.x;
    for (int e = blockIdx.x * blockDim.x + threadIdx.x; e < NE; e += stride)
        atomicAdd(&deg[dst[e]], 1);
}

__global__ void k_scan_part(const int* __restrict__ deg, int* __restrict__ partial) {
    __shared__ int sdata[256];
    int base = blockIdx.x * SCAN_CHUNK;
    int sum = 0;
    for (int j = threadIdx.x; j < SCAN_CHUNK; j += 256) {
        int idx = base + j;
        sum += (idx < NN) ? deg[idx] : 0;
    }
    sdata[threadIdx.x] = sum;
    __syncthreads();
    for (int s = 128; s > 0; s >>= 1) {
        if (threadIdx.x < s) sdata[threadIdx.x] += sdata[threadIdx.x + s];
        __syncthreads();
    }
    if (threadIdx.x == 0) partial[blockIdx.x] = sdata[0];
}

__global__ void k_scan_mid(int* __restrict__ partial) {
    if (threadIdx.x == 0) {
        int acc = 0;
        for (int i = 0; i < NB_SCAN; ++i) { int v = partial[i]; partial[i] = acc; acc += v; }
    }
}

__global__ void k_scan_final(const int* __restrict__ deg, const int* __restrict__ partial,
                             int* __restrict__ row_ptr, int* __restrict__ cursor) {
    __shared__ int svals[SCAN_CHUNK];
    __shared__ int ssum[256];
    int base = blockIdx.x * SCAN_CHUNK;
    for (int j = threadIdx.x; j < SCAN_CHUNK; j += 256) {
        int idx = base + j;
        svals[j] = (idx < NN) ? deg[idx] : 0;
    }
    __syncthreads();
    int t0 = threadIdx.x * 8;
    int loc[8];
    int s = 0;
#pragma unroll
    for (int k = 0; k < 8; ++k) { loc[k] = s; s += svals[t0 + k]; }
    ssum[threadIdx.x] = s;
    __syncthreads();
    // Hillis-Steele inclusive scan over 256 thread sums
    for (int off = 1; off < 256; off <<= 1) {
        int v = (threadIdx.x >= off) ? ssum[threadIdx.x - off] : 0;
        __syncthreads();
        ssum[threadIdx.x] += v;
        __syncthreads();
    }
    int texcl = (threadIdx.x == 0) ? 0 : ssum[threadIdx.x - 1];
    int offbase = partial[blockIdx.x] + texcl;
#pragma unroll
    for (int k = 0; k < 8; ++k) {
        int idx = base + t0 + k;
        if (idx < NN) {
            int v = offbase + loc[k];
            row_ptr[idx] = v;
            cursor[idx]  = v;
        }
    }
    if (blockIdx.x == 0 && threadIdx.x == 0) row_ptr[NN] = NE;
}

__global__ void k_fill(const int* __restrict__ src, const int* __restrict__ dst,
                       int* __restrict__ cursor, int* __restrict__ csr) {
    int stride = gridDim.x * blockDim.x;
    for (int e = blockIdx.x * blockDim.x + threadIdx.x; e < NE; e += stride) {
        int d = dst[e];
        int p = atomicAdd(&cursor[d], 1);
        csr[p] = src[e];
    }
}

// ---------------- aggregation: u[i] = hin[i] + sum_{j in N(i)} hin[j] ----------------
// 32 lanes (one half-wave) per node, float4 per lane -> one 512B coalesced row read per neighbor.
__global__ void k_agg(const float* __restrict__ hin, const int* __restrict__ row_ptr,
                      const int* __restrict__ csr, float* __restrict__ u) {
    int half = threadIdx.x >> 5;        // 0..7
    int l32  = threadIdx.x & 31;
    int node = blockIdx.x * 8 + half;
    if (node >= NN) return;
    const float4* rowin = (const float4*)(hin + (size_t)node * F);
    float4 acc = rowin[l32];
    int s = row_ptr[node], e = row_ptr[node + 1];
    for (int p = s; p < e; ++p) {
        int j = csr[p];
        float4 v = ((const float4*)(hin + (size_t)j * F))[l32];
        acc.x += v.x; acc.y += v.y; acc.z += v.z; acc.w += v.w;
    }
    ((float4*)(u + (size_t)node * F))[l32] = acc;
}

// ---------------- fp32 GEMM: C[M,128] = A[M,128] @ W[128,128] + bias (optional relu) --------
// block 256 threads, tile 128 rows x 128 cols, per-thread 8x8, BK=32, As transposed in LDS.
template <int RELU>
__global__ __launch_bounds__(256) void k_gemm(const float* __restrict__ A,
                                              const float* __restrict__ W,
                                              const float* __restrict__ bias,
                                              float* __restrict__ C) {
    __shared__ float As[32][132];   // [k][r], padded
    __shared__ float Bs[32][128];   // [k][c]
    int tid = threadIdx.x;
    int tx = tid & 15, ty = tid >> 4;
    int row0 = blockIdx.x * 128;
    int r0 = ty * 8, c0 = tx * 8;
    float acc[8][8] = {};

    for (int kt = 0; kt < 128; kt += 32) {
#pragma unroll
        for (int i = 0; i < 4; ++i) {
            int idx = tid + i * 256;          // 0..1023
            int r = idx >> 3, kv = idx & 7;   // r: 0..127, kv: float4 slot
            int grow = row0 + r;
            float4 v = make_float4(0.f, 0.f, 0.f, 0.f);
            if (grow < NN) v = *(const float4*)&A[(size_t)grow * F + kt + kv * 4];
            As[kv * 4 + 0][r] = v.x;
            As[kv * 4 + 1][r] = v.y;
            As[kv * 4 + 2][r] = v.z;
            As[kv * 4 + 3][r] = v.w;
        }
#pragma unroll
        for (int i = 0; i < 4; ++i) {
            int idx = tid + i * 256;          // float4 index over 32x128
            int k = idx >> 5, cv = idx & 31;
            *(float4*)&Bs[k][cv * 4] = *(const float4*)&W[(size_t)(kt + k) * F + cv * 4];
        }
        __syncthreads();
#pragma unroll
        for (int k = 0; k < 32; ++k) {
            float a[8], b[8];
            *(float4*)&a[0] = *(float4*)&As[k][r0];
            *(float4*)&a[4] = *(float4*)&As[k][r0 + 4];
            *(float4*)&b[0] = *(float4*)&Bs[k][c0];
            *(float4*)&b[4] = *(float4*)&Bs[k][c0 + 4];
#pragma unroll
            for (int i = 0; i < 8; ++i)
#pragma unroll
                for (int j = 0; j < 8; ++j)
                    acc[i][j] += a[i] * b[j];
        }
        __syncthreads();
    }

    float bv[8];
    *(float4*)&bv[0] = *(const float4*)&bias[c0];
    *(float4*)&bv[4] = *(const float4*)&bias[c0 + 4];
#pragma unroll
    for (int i = 0; i < 8; ++i) {
        int grow = row0 + r0 + i;
        if (grow >= NN) break;
        float o[8];
#pragma unroll
        for (int j = 0; j < 8; ++j) {
            float v = acc[i][j] + bv[j];
            o[j] = RELU ? fmaxf(v, 0.f) : v;
        }
        *(float4*)&C[(size_t)grow * F + c0]     = *(float4*)&o[0];
        *(float4*)&C[(size_t)grow * F + c0 + 4] = *(float4*)&o[4];
    }
}

// ---------------- final layer: out[i] = dot(t[i], w) + b ----------------
__global__ void k_final(const float* __restrict__ t, const float* __restrict__ w,
                        const float* __restrict__ b, float* __restrict__ out) {
    int wv = threadIdx.x >> 6;
    int lane = threadIdx.x & 63;
    int node = blockIdx.x * 4 + wv;
    if (node >= NN) return;
    float2 a  = ((const float2*)(t + (size_t)node * F))[lane];
    float2 ww = ((const float2*)w)[lane];
    float s = a.x * ww.x + a.y * ww.y;
#pragma unroll
    for (int off = 32; off > 0; off >>= 1) s += __shfl_down(s, off, 64);
    if (lane == 0) out[node] = s + b[0];
}

// ---------------- launch ----------------
static inline size_t align256(size_t x) { return (x + 255) & ~(size_t)255; }

extern "C" void kernel_launch(void* const* d_in, const int* in_sizes, int n_in,
                              void* d_out, int out_size, void* d_ws, size_t ws_size,
                              hipStream_t stream) {
    const float* x   = (const float*)d_in[0];
    const int*   ei  = (const int*)d_in[1];
    const float* w11 = (const float*)d_in[2];
    const float* b11 = (const float*)d_in[3];
    const float* w12 = (const float*)d_in[4];
    const float* b12 = (const float*)d_in[5];
    const float* w21 = (const float*)d_in[6];
    const float* b21 = (const float*)d_in[7];
    const float* w22 = (const float*)d_in[8];
    const float* b22 = (const float*)d_in[9];
    const float* w31 = (const float*)d_in[10];
    const float* b31 = (const float*)d_in[11];
    const float* w32 = (const float*)d_in[12];
    const float* b32 = (const float*)d_in[13];
    float* out = (float*)d_out;

    const int* src = ei;
    const int* dst = ei + NE;

    char* ws = (char*)d_ws;
    size_t off = 0;
    float* buf0 = (float*)(ws + off); off += align256((size_t)NN * F * 4);
    float* buf1 = (float*)(ws + off); off += align256((size_t)NN * F * 4);
    int* deg     = (int*)(ws + off); off += align256((size_t)NN * 4);
    int* row_ptr = (int*)(ws + off); off += align256((size_t)(NN + 1) * 4);
    int* cursor  = (int*)(ws + off); off += align256((size_t)NN * 4);
    int* partial = (int*)(ws + off); off += align256((size_t)NB_SCAN * 4);
    int* csr     = (int*)(ws + off); off += align256((size_t)NE * 4);
    (void)ws_size;

    // ---- CSR build ----
    hipMemsetAsync(deg, 0, (size_t)NN * 4, stream);
    k_hist<<<2048, 256, 0, stream>>>(dst, deg);
    k_scan_part<<<NB_SCAN, 256, 0, stream>>>(deg, partial);
    k_scan_mid<<<1, 64, 0, stream>>>(partial);
    k_scan_final<<<NB_SCAN, 256, 0, stream>>>(deg, partial, row_ptr, cursor);
    k_fill<<<2048, 256, 0, stream>>>(src, dst, cursor, csr);

    const int aggBlocks  = (NN + 7) / 8;
    const int gemmBlocks = (NN + 127) / 128;

    // ---- layer 1 ----
    k_agg<<<aggBlocks, 256, 0, stream>>>(x, row_ptr, csr, buf0);
    k_gemm<1><<<gemmBlocks, 256, 0, stream>>>(buf0, w11, b11, buf1);
    k_gemm<0><<<gemmBlocks, 256, 0, stream>>>(buf1, w12, b12, buf0);
    // ---- layer 2 ----
    k_agg<<<aggBlocks, 256, 0, stream>>>(buf0, row_ptr, csr, buf1);
    k_gemm<1><<<gemmBlocks, 256, 0, stream>>>(buf1, w21, b21, buf0);
    k_gemm<0><<<gemmBlocks, 256, 0, stream>>>(buf0, w22, b22, buf1);
    // ---- layer 3 ----
    k_agg<<<aggBlocks, 256, 0, stream>>>(buf1, row_ptr, csr, buf0);
    k_gemm<1><<<gemmBlocks, 256, 0, stream>>>(buf0, w31, b31, buf1);
    k_final<<<(NN + 3) / 4, 256, 0, stream>>>(buf1, w32, b32, out);
}